// Round 2
// 1068.786 us; speedup vs baseline: 1.0568x; 1.0568x over previous
//
#include <hip/hip_runtime.h>

#define BATCH 32
#define CIN   512
#define HH    112
#define WW    112
#define RC    32
#define CPG   16
#define HO    56
#define WO    56
#define TY    4
#define NTILE 14            // HO/TY
#define SPT   (TY*WO)       // 224 spatial outputs per block
#define XROWS 9             // staged input rows (2*TY+1)
#define XW    120           // staged row stride: 4 left-pad + 112 + 4 tail
#define TSP   228           // theta/phi tile row stride (224+4)
#define HW    (HH*WW)       // 12544
#define SHO   (HO*WO)       // 3136
#define NCHUNK 8            // channel chunks
#define GPC   (RC/NCHUNK)   // 4 groups per chunk
#define CPC   (GPC*CPG)     // 64 channels per chunk

// ws layout (float offsets)
#define WS_MAT 0
#define WS_GAP (BATCH*NTILE*RC*RC)                  // 458752 floats
#define WS_TH  (WS_GAP + BATCH*NTILE*RC)            // + 14336
#define WS_PH  (WS_TH + (size_t)BATCH*RC*SHO)       // + 3211264
#define WS_NEED_FLOATS (WS_PH + (size_t)BATCH*RC*SHO)
#define WS_NEED_BYTES  (WS_NEED_FLOATS * 4)          // ~27.6 MB
#define WS_FUSED_BYTES ((size_t)(WS_GAP + BATCH*NTILE*RC) * 4)  // ~1.85 MB

__device__ __forceinline__ float4 ldx(const float* p, bool pred) {
    float4 v = make_float4(0.f, 0.f, 0.f, 0.f);
    if (pred) v = *(const float4*)p;
    return v;
}

// ============================== SPLIT PATH ==================================
// One block = one (spatial row-tile, channel-chunk, batch). Computes grouped
// theta/phi convs for its 4 groups (64 channels) from a single staged read of x,
// writes theta/phi rows to global, and folds the fc(GAP) partial for its channels.
// x is read from HBM exactly once (+halo). Small LDS -> high occupancy.
__global__ __launch_bounds__(256, 4)
void conv_kernel(const float* __restrict__ x,
                 const float* __restrict__ thw, const float* __restrict__ thb,
                 const float* __restrict__ phw, const float* __restrict__ phb,
                 const float* __restrict__ fcw,
                 float* __restrict__ theta, float* __restrict__ phi,
                 float* __restrict__ gpart)
{
    const int t   = blockIdx.x;   // 0..13  spatial row tile
    const int ck  = blockIdx.y;   // 0..7   channel chunk
    const int b   = blockIdx.z;
    const int tid = threadIdx.x;
    const int c0  = ck * CPC;     // first global channel of this chunk

    __shared__ __align__(16) float xs[2][XROWS*XW];
    __shared__ float g_red[4*GPC];

    for (int r = tid; r < XROWS; r += 256) {
        #pragma unroll
        for (int k = 0; k < 4; ++k) {
            xs[0][r*XW + k] = 0.f;       xs[1][r*XW + k] = 0.f;
            xs[0][r*XW + 116 + k] = 0.f; xs[1][r*XW + 116 + k] = 0.f;
        }
    }

    // ---- staging geometry: 9 contiguous input rows = 1008 floats = 252 float4 ----
    const bool sact = tid < 252;
    const int  srow = (4*tid) / WW;          // 0..8 (local row)
    const int  scol = (4*tid) % WW;
    const bool oobz = (t == 0) && (srow == 0);   // input row -1 -> stage zeros
    const bool ldp  = sact && !oobz;
    const bool gapv = sact && (srow >= 1);       // rows 1..8 = GAP rows [8t,8t+8)
    const float* xbase = x + (size_t)b*CIN*HW + (size_t)c0*HW
                           + (long)(8*t - 1 + srow)*WW + scol;
    const int  sdst = srow*XW + 4 + scol;        // 16B aligned

    // ---- conv geometry ----
    const bool cact = tid < SPT;
    const int  ry   = tid / WO;                  // 0..3
    const int  ox   = tid - ry*WO;               // 0..55
    const int  cbase = (2*ry)*XW + 3 + 2*ox;     // local addr of (iy0, ix0) with pads

    // preamble: chunk-local channel 0 staged into xs[0]; prefetch cl=1, cl=2
    float4 v0 = ldx(xbase, ldp);
    if (sact) *(float4*)(&xs[0][sdst]) = v0;
    float gcur = gapv ? (v0.x + v0.y + v0.z + v0.w) * fcw[c0] : 0.f;
    float4 va = ldx(xbase + (size_t)1*HW, ldp);
    float4 vb = ldx(xbase + (size_t)2*HW, ldp);

    for (int gl = 0; gl < GPC; ++gl) {
        const int g = ck*GPC + gl;               // global group
        float tacc = thb[g];
        float pacc = phb[g];
        #pragma unroll 4
        for (int i = 0; i < CPG; ++i) {
            const int cl = gl*CPG + i;           // chunk-local channel
            const int ch = c0 + cl;              // global channel
            float4 vn = make_float4(0.f, 0.f, 0.f, 0.f);
            if (cl + 3 < CPC) vn = ldx(xbase + (size_t)(cl + 3)*HW, ldp);

            __syncthreads();   // xs[cl&1] fully staged; prev buffer reads done

            if (cact) {
                const float* xr = &xs[cl & 1][cbase];
                const float* wt = thw + ch*9;      // uniform -> scalar loads
                const float* wp = phw + ch*9;
                const float a0 = xr[0],      a1 = xr[1],      a2 = xr[2];
                const float b0 = xr[XW],     b1 = xr[XW+1],   b2 = xr[XW+2];
                const float c0v = xr[2*XW],  c1 = xr[2*XW+1], c2 = xr[2*XW+2];
                tacc = fmaf(a0, wt[0], tacc); pacc = fmaf(a0, wp[0], pacc);
                tacc = fmaf(a1, wt[1], tacc); pacc = fmaf(a1, wp[1], pacc);
                tacc = fmaf(a2, wt[2], tacc); pacc = fmaf(a2, wp[2], pacc);
                tacc = fmaf(b0, wt[3], tacc); pacc = fmaf(b0, wp[3], pacc);
                tacc = fmaf(b1, wt[4], tacc); pacc = fmaf(b1, wp[4], pacc);
                tacc = fmaf(b2, wt[5], tacc); pacc = fmaf(b2, wp[5], pacc);
                tacc = fmaf(c0v, wt[6], tacc); pacc = fmaf(c0v, wp[6], pacc);
                tacc = fmaf(c1, wt[7], tacc); pacc = fmaf(c1, wp[7], pacc);
                tacc = fmaf(c2, wt[8], tacc); pacc = fmaf(c2, wp[8], pacc);
            }

            if (i == CPG - 1) {
                if (cact) {
                    const size_t o = ((size_t)b*RC + g)*SHO + (size_t)t*SPT + tid;
                    theta[o] = tacc;
                    phi[o]   = pacc;
                }
                float r = gcur;
                #pragma unroll
                for (int off = 32; off; off >>= 1) r += __shfl_down(r, off);
                if ((tid & 63) == 0) g_red[(tid >> 6)*GPC + gl] = r;
                gcur = 0.f;
            }

            if (cl + 1 < CPC) {
                if (sact) *(float4*)(&xs[(cl + 1) & 1][sdst]) = va;
                if (gapv) gcur = fmaf(va.x + va.y + va.z + va.w, fcw[ch + 1], gcur);
                va = vb; vb = vn;
            }
        }
    }

    __syncthreads();   // g_red complete
    if (tid < GPC) {
        const float s = g_red[tid] + g_red[GPC + tid]
                      + g_red[2*GPC + tid] + g_red[3*GPC + tid];
        gpart[((size_t)b*NTILE + t)*RC + ck*GPC + tid] = s;
    }
}

// Gram partial for one (batch, spatial tile): stage theta/phi tiles from global,
// compute the 32x32 partial product over 224 spatial positions.
__global__ __launch_bounds__(256, 2)
void gram_kernel(const float* __restrict__ theta, const float* __restrict__ phi,
                 float* __restrict__ matpart)
{
    const int t   = blockIdx.x;   // 0..13
    const int b   = blockIdx.y;
    const int tid = threadIdx.x;

    __shared__ __align__(16) float th_s[RC*TSP];
    __shared__ __align__(16) float ph_s[RC*TSP];

    const int s0 = t*SPT;
    for (int idx = tid; idx < RC*(SPT/4); idx += 256) {
        const int g  = idx / (SPT/4);
        const int s4 = idx - g*(SPT/4);
        const size_t o = ((size_t)b*RC + g)*SHO + s0 + 4*s4;
        *(float4*)(&th_s[g*TSP + 4*s4]) = *(const float4*)(theta + o);
        *(float4*)(&ph_s[g*TSP + 4*s4]) = *(const float4*)(phi + o);
    }
    __syncthreads();

    const int c  = tid >> 3;
    const int dq = tid & 7;
    const float* tr = th_s + c*TSP;
    const float* p0 = ph_s + dq*TSP;
    float a0 = 0.f, a1 = 0.f, a2 = 0.f, a3 = 0.f;
    for (int s = 0; s < SPT; s += 4) {
        const float4 tv = *(const float4*)(tr + s);
        const float4 q0 = *(const float4*)(p0 + s);
        const float4 q1 = *(const float4*)(p0 + 8*TSP + s);
        const float4 q2 = *(const float4*)(p0 + 16*TSP + s);
        const float4 q3 = *(const float4*)(p0 + 24*TSP + s);
        a0 += tv.x*q0.x + tv.y*q0.y + tv.z*q0.z + tv.w*q0.w;
        a1 += tv.x*q1.x + tv.y*q1.y + tv.z*q1.z + tv.w*q1.w;
        a2 += tv.x*q2.x + tv.y*q2.y + tv.z*q2.z + tv.w*q2.w;
        a3 += tv.x*q3.x + tv.y*q3.y + tv.z*q3.z + tv.w*q3.w;
    }
    float* mp = matpart + ((size_t)b*NTILE + t)*(RC*RC) + c*RC + dq;
    mp[0]  = a0;
    mp[8]  = a1;
    mp[16] = a2;
    mp[24] = a3;
}

// ============================== FUSED FALLBACK ==============================
// Known-good baseline (1129 us): one block per (tile,batch), all 512 channels,
// Gram computed in-block. Used only when ws_size can't hold theta/phi.
__global__ __launch_bounds__(256, 2)
void conv_gram_kernel(const float* __restrict__ x,
                      const float* __restrict__ thw, const float* __restrict__ thb,
                      const float* __restrict__ phw, const float* __restrict__ phb,
                      const float* __restrict__ fcw,
                      float* __restrict__ matpart, float* __restrict__ gpart)
{
    const int t   = blockIdx.x;   // 0..13
    const int b   = blockIdx.y;
    const int tid = threadIdx.x;

    __shared__ __align__(16) float xs[2][XROWS*XW];
    __shared__ __align__(16) float th_s[RC*TSP];
    __shared__ __align__(16) float ph_s[RC*TSP];
    __shared__ float g_red[4*RC];

    for (int r = tid; r < XROWS; r += 256) {
        #pragma unroll
        for (int k = 0; k < 4; ++k) {
            xs[0][r*XW + k] = 0.f;       xs[1][r*XW + k] = 0.f;
            xs[0][r*XW + 116 + k] = 0.f; xs[1][r*XW + 116 + k] = 0.f;
        }
    }

    const bool sact = tid < 252;
    const int  srow = (4*tid) / WW;
    const int  scol = (4*tid) % WW;
    const bool oobz = (t == 0) && (srow == 0);
    const bool ldp  = sact && !oobz;
    const bool gapv = sact && (srow >= 1);
    const float* xbase = x + (size_t)b*CIN*HW + (long)(8*t - 1 + srow)*WW + scol;
    const int  sdst = srow*XW + 4 + scol;

    const bool cact = tid < SPT;
    const int  ry   = tid / WO;
    const int  ox   = tid - ry*WO;
    const int  cbase = (2*ry)*XW + 3 + 2*ox;

    float4 v0 = ldx(xbase, ldp);
    if (sact) *(float4*)(&xs[0][sdst]) = v0;
    float gcur = gapv ? (v0.x + v0.y + v0.z + v0.w) * fcw[0] : 0.f;
    float4 va = ldx(xbase + (size_t)1*HW, ldp);
    float4 vb = ldx(xbase + (size_t)2*HW, ldp);

    for (int g = 0; g < RC; ++g) {
        float tacc = thb[g];
        float pacc = phb[g];
        #pragma unroll 4
        for (int i = 0; i < CPG; ++i) {
            const int ch = g*CPG + i;
            float4 vn = make_float4(0.f, 0.f, 0.f, 0.f);
            if (ch + 3 < CIN) vn = ldx(xbase + (size_t)(ch + 3)*HW, ldp);

            __syncthreads();

            if (cact) {
                const float* xr = &xs[ch & 1][cbase];
                const float* wt = thw + ch*9;
                const float* wp = phw + ch*9;
                const float a0 = xr[0],      a1 = xr[1],      a2 = xr[2];
                const float b0 = xr[XW],     b1 = xr[XW+1],   b2 = xr[XW+2];
                const float c0 = xr[2*XW],   c1 = xr[2*XW+1], c2 = xr[2*XW+2];
                tacc = fmaf(a0, wt[0], tacc); pacc = fmaf(a0, wp[0], pacc);
                tacc = fmaf(a1, wt[1], tacc); pacc = fmaf(a1, wp[1], pacc);
                tacc = fmaf(a2, wt[2], tacc); pacc = fmaf(a2, wp[2], pacc);
                tacc = fmaf(b0, wt[3], tacc); pacc = fmaf(b0, wp[3], pacc);
                tacc = fmaf(b1, wt[4], tacc); pacc = fmaf(b1, wp[4], pacc);
                tacc = fmaf(b2, wt[5], tacc); pacc = fmaf(b2, wp[5], pacc);
                tacc = fmaf(c0, wt[6], tacc); pacc = fmaf(c0, wp[6], pacc);
                tacc = fmaf(c1, wt[7], tacc); pacc = fmaf(c1, wp[7], pacc);
                tacc = fmaf(c2, wt[8], tacc); pacc = fmaf(c2, wp[8], pacc);
            }

            if (i == CPG - 1) {
                if (cact) { th_s[g*TSP + tid] = tacc; ph_s[g*TSP + tid] = pacc; }
                float r = gcur;
                #pragma unroll
                for (int off = 32; off; off >>= 1) r += __shfl_down(r, off);
                if ((tid & 63) == 0) g_red[(tid >> 6)*RC + g] = r;
                gcur = 0.f;
            }

            if (ch + 1 < CIN) {
                if (sact) *(float4*)(&xs[(ch + 1) & 1][sdst]) = va;
                if (gapv) gcur = fmaf(va.x + va.y + va.z + va.w, fcw[ch + 1], gcur);
                va = vb; vb = vn;
            }
        }
    }

    __syncthreads();

    {
        const int c  = tid >> 3;
        const int dq = tid & 7;
        const float* tr = th_s + c*TSP;
        const float* p0 = ph_s + dq*TSP;
        float a0 = 0.f, a1 = 0.f, a2 = 0.f, a3 = 0.f;
        for (int s = 0; s < SPT; s += 4) {
            const float4 tv = *(const float4*)(tr + s);
            const float4 q0 = *(const float4*)(p0 + s);
            const float4 q1 = *(const float4*)(p0 + 8*TSP + s);
            const float4 q2 = *(const float4*)(p0 + 16*TSP + s);
            const float4 q3 = *(const float4*)(p0 + 24*TSP + s);
            a0 += tv.x*q0.x + tv.y*q0.y + tv.z*q0.z + tv.w*q0.w;
            a1 += tv.x*q1.x + tv.y*q1.y + tv.z*q1.z + tv.w*q1.w;
            a2 += tv.x*q2.x + tv.y*q2.y + tv.z*q2.z + tv.w*q2.w;
            a3 += tv.x*q3.x + tv.y*q3.y + tv.z*q3.z + tv.w*q3.w;
        }
        float* mp = matpart + ((size_t)b*NTILE + t)*(RC*RC) + c*RC + dq;
        mp[0]  = a0;
        mp[8]  = a1;
        mp[16] = a2;
        mp[24] = a3;
    }

    if (tid < RC) {
        const float s = g_red[tid] + g_red[RC + tid] + g_red[2*RC + tid] + g_red[3*RC + tid];
        gpart[((size_t)b*NTILE + t)*RC + tid] = s;
    }
}

// Reduce the 14 spatial partials, build g, softmax rows, emit [B,RC,1,1].
__global__ __launch_bounds__(256)
void final_kernel(const float* __restrict__ matpart, const float* __restrict__ gpart,
                  const float* __restrict__ fcb, float* __restrict__ out)
{
    const int b   = blockIdx.x;
    const int tid = threadIdx.x;
    __shared__ float m_s[RC*33];
    __shared__ float g_s[RC];

    for (int idx = tid; idx < RC*RC; idx += 256) {
        float s = 0.f;
        const float* mp = matpart + (size_t)b*NTILE*RC*RC + idx;
        #pragma unroll
        for (int tt = 0; tt < NTILE; ++tt) s += mp[tt*RC*RC];
        m_s[(idx >> 5)*33 + (idx & 31)] = s;
    }
    if (tid < RC) {
        float s = 0.f;
        const float* gp = gpart + (size_t)b*NTILE*RC + tid;
        #pragma unroll
        for (int tt = 0; tt < NTILE; ++tt) s += gp[tt*RC];
        g_s[tid] = fcb[tid] + s * (1.0f/(float)HW);
    }
    __syncthreads();
    if (tid < RC) {
        const float* row = m_s + tid*33;
        float m = -1e30f;
        for (int d = 0; d < RC; ++d) m = fmaxf(m, row[d]);
        float se = 0.f, num = 0.f;
        for (int d = 0; d < RC; ++d) {
            const float e = expf(row[d] - m);
            se  += e;
            num += e * g_s[d];
        }
        out[b*RC + tid] = num / se;
    }
}

extern "C" void kernel_launch(void* const* d_in, const int* in_sizes, int n_in,
                              void* d_out, int out_size, void* d_ws, size_t ws_size,
                              hipStream_t stream)
{
    const float* x   = (const float*)d_in[0];
    const float* thw = (const float*)d_in[1];
    const float* thb = (const float*)d_in[2];
    const float* phw = (const float*)d_in[3];
    const float* phb = (const float*)d_in[4];
    const float* fcw = (const float*)d_in[5];
    const float* fcb = (const float*)d_in[6];
    float* out = (float*)d_out;
    float* ws  = (float*)d_ws;

    float* matpart = ws + WS_MAT;
    float* gpart   = ws + WS_GAP;

    if (ws_size >= (size_t)WS_NEED_BYTES) {
        // split path: high-occupancy conv, then Gram from materialized theta/phi
        float* theta = ws + WS_TH;
        float* phi   = ws + WS_PH;
        conv_kernel<<<dim3(NTILE, NCHUNK, BATCH), 256, 0, stream>>>(
            x, thw, thb, phw, phb, fcw, theta, phi, gpart);
        gram_kernel<<<dim3(NTILE, BATCH), 256, 0, stream>>>(theta, phi, matpart);
    } else {
        // fallback: known-good fused kernel (fits in ~1.85 MB workspace)
        conv_gram_kernel<<<dim3(NTILE, BATCH), 256, 0, stream>>>(
            x, thw, thb, phw, phb, fcw, matpart, gpart);
    }
    final_kernel<<<BATCH, 256, 0, stream>>>(matpart, gpart, fcb, out);
}